// Round 3
// baseline (2626.480 us; speedup 1.0000x reference)
//
#include <hip/hip_runtime.h>
#include <math.h>

#define DIM 64
#define NT 4
#define NR 8

// ---------------- init: den = 0, agg = 0 ----------------
__global__ void init_kernel(float* __restrict__ den, float* __restrict__ agg, int N) {
    int i = blockIdx.x * blockDim.x + threadIdx.x;
    if (i < N * DIM) agg[i] = 0.f;
    if (i < N) den[i] = 0.f;
}

// ------------- fused per-node-type K/Q/V projections -------------
__global__ void proj_kqv(const float* __restrict__ h, const int* __restrict__ ntype,
                         const float* __restrict__ Wk, const float* __restrict__ Wq,
                         const float* __restrict__ Wv,
                         float* __restrict__ k, float* __restrict__ q,
                         float* __restrict__ v, int N) {
    __shared__ float hs[4][DIM];
    int ln = threadIdx.x >> 6;
    int o  = threadIdx.x & 63;
    int n  = blockIdx.x * 4 + ln;
    float hv = 0.f;
    if (n < N) hv = h[(size_t)n * DIM + o];
    hs[ln][o] = hv;
    __syncthreads();
    if (n >= N) return;
    int t = ntype[n];
    const float* wk = Wk + (size_t)t * DIM * DIM;
    const float* wq = Wq + (size_t)t * DIM * DIM;
    const float* wv = Wv + (size_t)t * DIM * DIM;
    float ak = 0.f, aq = 0.f, av = 0.f;
    #pragma unroll 16
    for (int d = 0; d < DIM; d++) {
        float x = hs[ln][d];
        ak = fmaf(x, wk[d * DIM + o], ak);
        aq = fmaf(x, wq[d * DIM + o], aq);
        av = fmaf(x, wv[d * DIM + o], av);
    }
    k[(size_t)n * DIM + o] = ak;
    q[(size_t)n * DIM + o] = aq;
    v[(size_t)n * DIM + o] = av;
}

// --------- out[ry][n][o] = sum_d x[n][d] * Wr[r0+ry][d][o] ---------
__global__ void apply_rel(const float* __restrict__ x, const float* __restrict__ Wr,
                          float* __restrict__ out, int N, int r0) {
    __shared__ float xs[4][DIM];
    int ry = blockIdx.y;
    int ln = threadIdx.x >> 6;
    int o  = threadIdx.x & 63;
    int n  = blockIdx.x * 4 + ln;
    float xv = 0.f;
    if (n < N) xv = x[(size_t)n * DIM + o];
    xs[ln][o] = xv;
    __syncthreads();
    if (n >= N) return;
    const float* w = Wr + (size_t)(r0 + ry) * DIM * DIM;
    float acc = 0.f;
    #pragma unroll 16
    for (int d = 0; d < DIM; d++)
        acc = fmaf(xs[ln][d], w[d * DIM + o], acc);
    out[((size_t)ry * N + n) * DIM + o] = acc;
}

// ------- score (chunked): 16 lanes per edge, float4 row loads -------
// logits are tiny (|x| < ~1) by input scaling -> exp without max-subtraction
// is safe and matches the reference softmax exactly (shift-invariance).
__global__ void score_chunk(const float* __restrict__ qW, const float* __restrict__ k,
                            const int* __restrict__ src, const int* __restrict__ dst,
                            const int* __restrict__ et, const float* __restrict__ rel_pri,
                            float* __restrict__ ex, float* __restrict__ den,
                            int N, int E, int r0, int r1) {
    int eg = blockIdx.x * (blockDim.x >> 4) + (threadIdx.x >> 4);
    int ll = threadIdx.x & 15;
    if (eg >= E) return;
    int r = et[eg];
    if (r < r0 || r >= r1) return;
    int s = src[eg], d = dst[eg];
    const float4* qrow = (const float4*)(qW + ((size_t)(r - r0) * N + d) * DIM);
    const float4* krow = (const float4*)(k + (size_t)s * DIM);
    float4 a = qrow[ll];
    float4 b = krow[ll];
    float p = a.x * b.x + a.y * b.y + a.z * b.z + a.w * b.w;
    #pragma unroll
    for (int off = 8; off > 0; off >>= 1) p += __shfl_xor(p, off, 64);
    if (ll == 0) {
        float e_ = expf(p * rel_pri[r] * 0.125f);  // / sqrt(64)
        ex[eg] = e_;
        atomicAdd(&den[d], e_);
    }
}

// ------- direct (fallback, no qW buffer): per-edge bilinear -------
__global__ void score_direct(const float* __restrict__ q, const float* __restrict__ k,
                             const int* __restrict__ src, const int* __restrict__ dst,
                             const int* __restrict__ et, const float* __restrict__ A,
                             const float* __restrict__ rel_pri,
                             float* __restrict__ ex, float* __restrict__ den, int E) {
    int e = (blockIdx.x * blockDim.x + threadIdx.x) >> 6;
    int l = threadIdx.x & 63;
    if (e >= E) return;
    int s = src[e], d = dst[e], r = et[e];
    float qv = q[(size_t)d * DIM + l];
    const float* a = A + (size_t)r * DIM * DIM;
    float t = 0.f;
    #pragma unroll 16
    for (int dd = 0; dd < DIM; dd++)
        t = fmaf(__shfl(qv, dd, 64), a[dd * DIM + l], t);
    float p = t * k[(size_t)s * DIM + l];
    #pragma unroll
    for (int off = 32; off > 0; off >>= 1) p += __shfl_xor(p, off, 64);
    if (l == 0) {
        float e_ = expf(p * rel_pri[r] * 0.125f);
        ex[e] = e_;
        atomicAdd(&den[d], e_);
    }
}

// ------- aggregate (chunked): 16 lanes per edge, float4 gather -------
__global__ void agg_chunk(const float* __restrict__ vW, const float* __restrict__ ex,
                          const int* __restrict__ src, const int* __restrict__ dst,
                          const int* __restrict__ et, const float* __restrict__ den,
                          float* __restrict__ agg, int N, int E, int r0, int r1) {
    int eg = blockIdx.x * (blockDim.x >> 4) + (threadIdx.x >> 4);
    int ll = threadIdx.x & 15;
    if (eg >= E) return;
    int r = et[eg];
    if (r < r0 || r >= r1) return;
    int s = src[eg], d = dst[eg];
    float alpha = ex[eg] / den[d];  // den > 0: this edge contributed
    float4 mv = ((const float4*)(vW + ((size_t)(r - r0) * N + s) * DIM))[ll];
    float* ap = agg + (size_t)d * DIM + ll * 4;
    atomicAdd(ap + 0, alpha * mv.x);
    atomicAdd(ap + 1, alpha * mv.y);
    atomicAdd(ap + 2, alpha * mv.z);
    atomicAdd(ap + 3, alpha * mv.w);
}

// ------- direct (fallback): aggregate via per-edge bilinear -------
__global__ void agg_direct(const float* __restrict__ v, const float* __restrict__ ex,
                           const int* __restrict__ src, const int* __restrict__ dst,
                           const int* __restrict__ et, const float* __restrict__ Mw,
                           const float* __restrict__ den,
                           float* __restrict__ agg, int E) {
    int e = (blockIdx.x * blockDim.x + threadIdx.x) >> 6;
    int l = threadIdx.x & 63;
    if (e >= E) return;
    int s = src[e], d = dst[e], r = et[e];
    float vv = v[(size_t)s * DIM + l];
    const float* w = Mw + (size_t)r * DIM * DIM;
    float t = 0.f;
    #pragma unroll 16
    for (int dd = 0; dd < DIM; dd++)
        t = fmaf(__shfl(vv, dd, 64), w[dd * DIM + l], t);
    float alpha = ex[e] / den[d];
    atomicAdd(&agg[(size_t)d * DIM + l], alpha * t);
}

// ------- output: per-node-type GEMM with sigmoid(skip) scaling -------
__global__ void out_kernel(const float* __restrict__ agg, const int* __restrict__ ntype,
                           const float* __restrict__ Wa, const float* __restrict__ skip,
                           float* __restrict__ out, int N) {
    __shared__ float xs[4][DIM];
    int ln = threadIdx.x >> 6;
    int o  = threadIdx.x & 63;
    int n  = blockIdx.x * 4 + ln;
    float xv = 0.f;
    if (n < N) xv = agg[(size_t)n * DIM + o];
    xs[ln][o] = xv;
    __syncthreads();
    if (n >= N) return;
    int t = ntype[n];
    float sg = 1.f / (1.f + expf(-skip[t]));
    const float* w = Wa + (size_t)t * DIM * DIM;
    float acc = 0.f;
    #pragma unroll 16
    for (int d = 0; d < DIM; d++)
        acc = fmaf(xs[ln][d], w[d * DIM + o], acc);
    out[(size_t)n * DIM + o] = acc * sg;
}

extern "C" void kernel_launch(void* const* d_in, const int* in_sizes, int n_in,
                              void* d_out, int out_size, void* d_ws, size_t ws_size,
                              hipStream_t stream) {
    const float* h       = (const float*)d_in[0];
    const int*   ntype   = (const int*)  d_in[1];
    const int*   src     = (const int*)  d_in[2];
    const int*   dst     = (const int*)  d_in[3];
    const int*   et      = (const int*)  d_in[4];
    const float* k_lin   = (const float*)d_in[5];
    const float* q_lin   = (const float*)d_in[6];
    const float* v_lin   = (const float*)d_in[7];
    const float* a_lin   = (const float*)d_in[8];
    const float* rel_att = (const float*)d_in[9];
    const float* rel_msg = (const float*)d_in[10];
    const float* rel_pri = (const float*)d_in[11];
    const float* skip    = (const float*)d_in[12];

    int N = in_sizes[1];   // node_type
    int E = in_sizes[2];   // src

    float* ws = (float*)d_ws;
    size_t off = 0;
    float* k      = ws + off; off += (size_t)N * DIM;
    float* q      = ws + off; off += (size_t)N * DIM;
    float* v      = ws + off; off += (size_t)N * DIM;
    float* ex     = ws + off; off += (size_t)E;
    float* den    = ws + off; off += (size_t)N;
    float* agg    = ws + off; off += (size_t)N * DIM;
    size_t fixed  = off;

    size_t ws_floats = ws_size / sizeof(float);
    size_t avail = (ws_floats > fixed) ? (ws_floats - fixed) : 0;
    int C = (int)(avail / ((size_t)N * DIM));
    if (C > NR) C = NR;
    float* rbuf = ws + fixed;   // C relations of [N x DIM]

    float* out = (float*)d_out;

    init_kernel<<<(N * DIM + 255) / 256, 256, 0, stream>>>(den, agg, N);
    proj_kqv<<<(N + 3) / 4, 256, 0, stream>>>(h, ntype, k_lin, q_lin, v_lin, k, q, v, N);

    int eb16 = (E + 15) / 16;  // 16 edges per 256-thread block
    int eb64 = (E + 3) / 4;    // wave-per-edge blocks (fallback)

    if (C >= 1) {
        for (int r0 = 0; r0 < NR; r0 += C) {
            int r1 = r0 + C < NR ? r0 + C : NR;
            apply_rel<<<dim3((N + 3) / 4, r1 - r0), 256, 0, stream>>>(q, rel_att, rbuf, N, r0);
            score_chunk<<<eb16, 256, 0, stream>>>(rbuf, k, src, dst, et, rel_pri,
                                                  ex, den, N, E, r0, r1);
        }
        for (int r0 = 0; r0 < NR; r0 += C) {
            int r1 = r0 + C < NR ? r0 + C : NR;
            apply_rel<<<dim3((N + 3) / 4, r1 - r0), 256, 0, stream>>>(v, rel_msg, rbuf, N, r0);
            agg_chunk<<<eb16, 256, 0, stream>>>(rbuf, ex, src, dst, et, den,
                                                agg, N, E, r0, r1);
        }
    } else {
        score_direct<<<eb64, 256, 0, stream>>>(q, k, src, dst, et, rel_att, rel_pri,
                                               ex, den, E);
        agg_direct<<<eb64, 256, 0, stream>>>(v, ex, src, dst, et, rel_msg,
                                             den, agg, E);
    }

    out_kernel<<<(N + 3) / 4, 256, 0, stream>>>(agg, ntype, a_lin, skip, out, N);
}

// Round 4
// 1673.582 us; speedup vs baseline: 1.5694x; 1.5694x over previous
//
#include <hip/hip_runtime.h>
#include <math.h>

#define DIM 64
#define NT 4
#define NR 8
#define SRC_MASK 0x00FFFFFF

// ---------------- zero int buffers (cnt, cnt2) ----------------
__global__ void init_cnt(int* __restrict__ cnt, int* __restrict__ cnt2, int N) {
    int i = blockIdx.x * blockDim.x + threadIdx.x;
    if (i < N) { cnt[i] = 0; cnt2[i] = 0; }
}

__global__ void zero_f(float* __restrict__ p, int n) {
    int i = blockIdx.x * blockDim.x + threadIdx.x;
    if (i < n) p[i] = 0.f;
}

// ------------- fused per-node-type K/Q/V projections -------------
__global__ void proj_kqv(const float* __restrict__ h, const int* __restrict__ ntype,
                         const float* __restrict__ Wk, const float* __restrict__ Wq,
                         const float* __restrict__ Wv,
                         float* __restrict__ k, float* __restrict__ q,
                         float* __restrict__ v, int N) {
    __shared__ float hs[4][DIM];
    int ln = threadIdx.x >> 6;
    int o  = threadIdx.x & 63;
    int n  = blockIdx.x * 4 + ln;
    float hv = 0.f;
    if (n < N) hv = h[(size_t)n * DIM + o];
    hs[ln][o] = hv;
    __syncthreads();
    if (n >= N) return;
    int t = ntype[n];
    const float* wk = Wk + (size_t)t * DIM * DIM;
    const float* wq = Wq + (size_t)t * DIM * DIM;
    const float* wv = Wv + (size_t)t * DIM * DIM;
    float ak = 0.f, aq = 0.f, av = 0.f;
    #pragma unroll 16
    for (int d = 0; d < DIM; d++) {
        float x = hs[ln][d];
        ak = fmaf(x, wk[d * DIM + o], ak);
        aq = fmaf(x, wq[d * DIM + o], aq);
        av = fmaf(x, wv[d * DIM + o], av);
    }
    k[(size_t)n * DIM + o] = ak;
    q[(size_t)n * DIM + o] = aq;
    v[(size_t)n * DIM + o] = av;
}

// ---------------- CSR build: histogram of dst ----------------
__global__ void hist_kernel(const int* __restrict__ dst, int* __restrict__ cnt, int E) {
    int e = blockIdx.x * blockDim.x + threadIdx.x;
    if (e < E) atomicAdd(&cnt[dst[e]], 1);
}

// ------- single-block tiled exclusive scan: cnt[N] -> off[N+1] -------
__global__ void scan_kernel(const int* __restrict__ cnt, int* __restrict__ off, int N) {
    __shared__ int buf[1024];
    __shared__ int carry;
    int tid = threadIdx.x;
    if (tid == 0) carry = 0;
    __syncthreads();
    for (int base = 0; base < N; base += 1024) {
        int i = base + tid;
        int x = (i < N) ? cnt[i] : 0;
        buf[tid] = x;
        __syncthreads();
        for (int s = 1; s < 1024; s <<= 1) {
            int t = (tid >= s) ? buf[tid - s] : 0;
            __syncthreads();
            buf[tid] += t;
            __syncthreads();
        }
        if (i < N) off[i] = carry + buf[tid] - x;   // exclusive
        __syncthreads();
        if (tid == 1023) carry += buf[1023];
        __syncthreads();
    }
    if (tid == 0) off[N] = carry;                    // == E
}

// ------- scatter edges into dst-sorted order; pack (et<<24)|src -------
__global__ void scatter_kernel(const int* __restrict__ src, const int* __restrict__ dst,
                               const int* __restrict__ et, const int* __restrict__ off,
                               int* __restrict__ cnt2, int* __restrict__ se, int E) {
    int e = blockIdx.x * blockDim.x + threadIdx.x;
    if (e >= E) return;
    int d = dst[e];
    int p = off[d] + atomicAdd(&cnt2[d], 1);
    se[p] = (et[e] << 24) | src[e];
}

// --------- out[ry][n][o] = sum_d x[n][d] * Wr[r0+ry][d][o], float4 ---------
__global__ void apply_rel4(const float* __restrict__ x, const float* __restrict__ Wr,
                           float* __restrict__ out, int N, int r0) {
    __shared__ float xs[16][DIM];
    int t   = threadIdx.x;
    int ln  = t >> 4;            // node-in-block 0..15
    int og  = t & 15;            // float4 column group
    // cooperative load: thread t loads float4 #t of the 16x64 tile
    int row = t >> 4, c4 = t & 15;
    int gn  = blockIdx.x * 16 + row;
    float4 xv = make_float4(0.f, 0.f, 0.f, 0.f);
    if (gn < N) xv = ((const float4*)(x + (size_t)gn * DIM))[c4];
    ((float4*)&xs[row][0])[c4] = xv;
    __syncthreads();
    int n = blockIdx.x * 16 + ln;
    if (n >= N) return;
    int ry = blockIdx.y;
    const float* w = Wr + (size_t)(r0 + ry) * DIM * DIM;
    float4 acc = make_float4(0.f, 0.f, 0.f, 0.f);
    #pragma unroll 16
    for (int d = 0; d < DIM; d++) {
        float xx = xs[ln][d];
        float4 wv = ((const float4*)(w + d * DIM))[og];
        acc.x = fmaf(xx, wv.x, acc.x);
        acc.y = fmaf(xx, wv.y, acc.y);
        acc.z = fmaf(xx, wv.z, acc.z);
        acc.w = fmaf(xx, wv.w, acc.w);
    }
    ((float4*)(out + ((size_t)ry * N + n) * DIM))[og] = acc;
}

// ------- score over CSR: 16-lane group per dst node, no atomics -------
__global__ void score_csr(const float* __restrict__ qW, const float* __restrict__ k,
                          const int* __restrict__ se, const int* __restrict__ off,
                          const float* __restrict__ rel_pri,
                          float* __restrict__ ex, int N, int r0, int r1) {
    int n  = blockIdx.x * 16 + (threadIdx.x >> 4);
    int ll = threadIdx.x & 15;
    if (n >= N) return;
    int i0 = off[n], i1 = off[n + 1];
    for (int i = i0; i < i1; i++) {
        int sev = se[i];
        int r = sev >> 24;
        if (r < r0 || r >= r1) continue;
        int s = sev & SRC_MASK;
        float4 a = ((const float4*)(qW + ((size_t)(r - r0) * N + n) * DIM))[ll];
        float4 b = ((const float4*)(k + (size_t)s * DIM))[ll];
        float p = a.x * b.x + a.y * b.y + a.z * b.z + a.w * b.w;
        p += __shfl_xor(p, 8, 16);
        p += __shfl_xor(p, 4, 16);
        p += __shfl_xor(p, 2, 16);
        p += __shfl_xor(p, 1, 16);
        if (ll == 0) ex[i] = expf(p * rel_pri[r] * 0.125f);  // logits tiny: no max-shift needed
    }
}

// ------- per-node denominator over CSR range, no atomics -------
__global__ void den_csr(const float* __restrict__ ex, const int* __restrict__ off,
                        float* __restrict__ den, int N) {
    int n = blockIdx.x * blockDim.x + threadIdx.x;
    if (n >= N) return;
    int i0 = off[n], i1 = off[n + 1];
    float s = 0.f;
    for (int i = i0; i < i1; i++) s += ex[i];
    den[n] = s;
}

// ------- aggregate over CSR: 16-lane group per dst node, no atomics -------
__global__ void agg_csr(const float* __restrict__ vW, const float* __restrict__ ex,
                        const int* __restrict__ se, const int* __restrict__ off,
                        const float* __restrict__ den, float* __restrict__ agg,
                        int N, int r0, int r1, int first) {
    int n  = blockIdx.x * 16 + (threadIdx.x >> 4);
    int ll = threadIdx.x & 15;
    if (n >= N) return;
    int i0 = off[n], i1 = off[n + 1];
    float dn = den[n];
    float inv = (dn == 0.f) ? 0.f : 1.f / dn;
    float4 acc = make_float4(0.f, 0.f, 0.f, 0.f);
    for (int i = i0; i < i1; i++) {
        int sev = se[i];
        int r = sev >> 24;
        if (r < r0 || r >= r1) continue;
        int s = sev & SRC_MASK;
        float alpha = ex[i] * inv;
        float4 mv = ((const float4*)(vW + ((size_t)(r - r0) * N + s) * DIM))[ll];
        acc.x = fmaf(alpha, mv.x, acc.x);
        acc.y = fmaf(alpha, mv.y, acc.y);
        acc.z = fmaf(alpha, mv.z, acc.z);
        acc.w = fmaf(alpha, mv.w, acc.w);
    }
    float4* ap = (float4*)(agg + (size_t)n * DIM) + ll;
    if (first) *ap = acc;
    else {
        float4 o = *ap;
        o.x += acc.x; o.y += acc.y; o.z += acc.z; o.w += acc.w;
        *ap = o;
    }
}

// ------- output: per-node-type GEMM with sigmoid(skip) scaling -------
__global__ void out_kernel(const float* __restrict__ agg, const int* __restrict__ ntype,
                           const float* __restrict__ Wa, const float* __restrict__ skip,
                           float* __restrict__ out, int N) {
    __shared__ float xs[4][DIM];
    int ln = threadIdx.x >> 6;
    int o  = threadIdx.x & 63;
    int n  = blockIdx.x * 4 + ln;
    float xv = 0.f;
    if (n < N) xv = agg[(size_t)n * DIM + o];
    hs_store: ;
    xs[ln][o] = xv;
    __syncthreads();
    if (n >= N) return;
    int t = ntype[n];
    float sg = 1.f / (1.f + expf(-skip[t]));
    const float* w = Wa + (size_t)t * DIM * DIM;
    float acc = 0.f;
    #pragma unroll 16
    for (int d = 0; d < DIM; d++)
        acc = fmaf(xs[ln][d], w[d * DIM + o], acc);
    out[(size_t)n * DIM + o] = acc * sg;
}

// ------- fallback (tiny ws): per-edge bilinear with atomics -------
__global__ void score_direct(const float* __restrict__ q, const float* __restrict__ k,
                             const int* __restrict__ src, const int* __restrict__ dst,
                             const int* __restrict__ et, const float* __restrict__ A,
                             const float* __restrict__ rel_pri,
                             float* __restrict__ ex, float* __restrict__ den, int E) {
    int e = (blockIdx.x * blockDim.x + threadIdx.x) >> 6;
    int l = threadIdx.x & 63;
    if (e >= E) return;
    int s = src[e], d = dst[e], r = et[e];
    float qv = q[(size_t)d * DIM + l];
    const float* a = A + (size_t)r * DIM * DIM;
    float t = 0.f;
    #pragma unroll 16
    for (int dd = 0; dd < DIM; dd++)
        t = fmaf(__shfl(qv, dd, 64), a[dd * DIM + l], t);
    float p = t * k[(size_t)s * DIM + l];
    #pragma unroll
    for (int off = 32; off > 0; off >>= 1) p += __shfl_xor(p, off, 64);
    if (l == 0) {
        float e_ = expf(p * rel_pri[r] * 0.125f);
        ex[e] = e_;
        atomicAdd(&den[d], e_);
    }
}

__global__ void agg_direct(const float* __restrict__ v, const float* __restrict__ ex,
                           const int* __restrict__ src, const int* __restrict__ dst,
                           const int* __restrict__ et, const float* __restrict__ Mw,
                           const float* __restrict__ den,
                           float* __restrict__ agg, int E) {
    int e = (blockIdx.x * blockDim.x + threadIdx.x) >> 6;
    int l = threadIdx.x & 63;
    if (e >= E) return;
    int s = src[e], d = dst[e], r = et[e];
    float vv = v[(size_t)s * DIM + l];
    const float* w = Mw + (size_t)r * DIM * DIM;
    float t = 0.f;
    #pragma unroll 16
    for (int dd = 0; dd < DIM; dd++)
        t = fmaf(__shfl(vv, dd, 64), w[dd * DIM + l], t);
    float dn = den[d];
    float alpha = ex[e] / (dn == 0.f ? 1.f : dn);
    atomicAdd(&agg[(size_t)d * DIM + l], alpha * t);
}

extern "C" void kernel_launch(void* const* d_in, const int* in_sizes, int n_in,
                              void* d_out, int out_size, void* d_ws, size_t ws_size,
                              hipStream_t stream) {
    const float* h       = (const float*)d_in[0];
    const int*   ntype   = (const int*)  d_in[1];
    const int*   src     = (const int*)  d_in[2];
    const int*   dst     = (const int*)  d_in[3];
    const int*   et      = (const int*)  d_in[4];
    const float* k_lin   = (const float*)d_in[5];
    const float* q_lin   = (const float*)d_in[6];
    const float* v_lin   = (const float*)d_in[7];
    const float* a_lin   = (const float*)d_in[8];
    const float* rel_att = (const float*)d_in[9];
    const float* rel_msg = (const float*)d_in[10];
    const float* rel_pri = (const float*)d_in[11];
    const float* skip    = (const float*)d_in[12];

    int N = in_sizes[1];   // node_type
    int E = in_sizes[2];   // src

    float* ws = (float*)d_ws;
    size_t o = 0;
    float* k    = ws + o; o += (size_t)N * DIM;   // overlaid by agg later
    float* q    = ws + o; o += (size_t)N * DIM;   // overlaid by den later
    float* v    = ws + o; o += (size_t)N * DIM;
    float* ex   = ws + o; o += (size_t)E;
    int*   off  = (int*)(ws + o); o += (size_t)N + 1;
    int*   cnt  = (int*)(ws + o); o += (size_t)N;
    int*   cnt2 = (int*)(ws + o); o += (size_t)N;
    int*   se   = (int*)(ws + o); o += (size_t)E;
    size_t fixed = o;
    float* agg = k;   // k dead after score phase
    float* den = q;   // q dead after score-side apply_rel

    size_t ws_floats = ws_size / sizeof(float);
    size_t avail = (ws_floats > fixed) ? (ws_floats - fixed) : 0;
    int C = (int)(avail / ((size_t)N * DIM));
    if (C > NR) C = NR;
    float* rbuf = ws + fixed;

    float* out = (float*)d_out;

    proj_kqv<<<(N + 3) / 4, 256, 0, stream>>>(h, ntype, k_lin, q_lin, v_lin, k, q, v, N);

    if (C >= 1) {
        // ---- CSR build ----
        init_cnt<<<(N + 255) / 256, 256, 0, stream>>>(cnt, cnt2, N);
        hist_kernel<<<(E + 255) / 256, 256, 0, stream>>>(dst, cnt, E);
        scan_kernel<<<1, 1024, 0, stream>>>(cnt, off, N);
        scatter_kernel<<<(E + 255) / 256, 256, 0, stream>>>(src, dst, et, off, cnt2, se, E);

        int nb16 = (N + 15) / 16;
        // ---- score phase (chunked over relations) ----
        for (int r0 = 0; r0 < NR; r0 += C) {
            int r1 = r0 + C < NR ? r0 + C : NR;
            apply_rel4<<<dim3(nb16, r1 - r0), 256, 0, stream>>>(q, rel_att, rbuf, N, r0);
            score_csr<<<nb16, 256, 0, stream>>>(rbuf, k, se, off, rel_pri, ex, N, r0, r1);
        }
        den_csr<<<(N + 255) / 256, 256, 0, stream>>>(ex, off, den, N);
        // ---- aggregate phase ----
        for (int r0 = 0; r0 < NR; r0 += C) {
            int r1 = r0 + C < NR ? r0 + C : NR;
            apply_rel4<<<dim3(nb16, r1 - r0), 256, 0, stream>>>(v, rel_msg, rbuf, N, r0);
            agg_csr<<<nb16, 256, 0, stream>>>(rbuf, ex, se, off, den, agg, N, r0, r1,
                                              r0 == 0 ? 1 : 0);
        }
    } else {
        // ---- workspace-starved fallback: per-edge bilinear with atomics ----
        float* den_fb = (float*)cnt;   // N floats, zeroed below
        zero_f<<<(N + 255) / 256, 256, 0, stream>>>(den_fb, N);
        score_direct<<<(E + 3) / 4, 256, 0, stream>>>(q, k, src, dst, et, rel_att, rel_pri,
                                                      ex, den_fb, E);
        zero_f<<<(N * DIM + 255) / 256, 256, 0, stream>>>(agg, N * DIM);
        agg_direct<<<(E + 3) / 4, 256, 0, stream>>>(v, ex, src, dst, et, rel_msg,
                                                    den_fb, agg, E);
        den = den_fb;
    }

    out_kernel<<<(N + 3) / 4, 256, 0, stream>>>(agg, ntype, a_lin, skip, out, N);
}

// Round 5
// 981.622 us; speedup vs baseline: 2.6757x; 1.7049x over previous
//
#include <hip/hip_runtime.h>
#include <math.h>

#define DIM 64
#define NT 4
#define NR 8
#define SRC_MASK 0x00FFFFFF

// ---------------- zero int buffers (cnt, cnt2) ----------------
__global__ void init_cnt(int* __restrict__ cnt, int* __restrict__ cnt2, int N) {
    int i = blockIdx.x * blockDim.x + threadIdx.x;
    if (i < N) { cnt[i] = 0; cnt2[i] = 0; }
}

__global__ void zero_f(float* __restrict__ p, int n) {
    int i = blockIdx.x * blockDim.x + threadIdx.x;
    if (i < n) p[i] = 0.f;
}

// ------------- fused per-node-type K/Q/V projections -------------
__global__ void proj_kqv(const float* __restrict__ h, const int* __restrict__ ntype,
                         const float* __restrict__ Wk, const float* __restrict__ Wq,
                         const float* __restrict__ Wv,
                         float* __restrict__ k, float* __restrict__ q,
                         float* __restrict__ v, int N) {
    __shared__ float hs[4][DIM];
    int ln = threadIdx.x >> 6;
    int o  = threadIdx.x & 63;
    int n  = blockIdx.x * 4 + ln;
    float hv = 0.f;
    if (n < N) hv = h[(size_t)n * DIM + o];
    hs[ln][o] = hv;
    __syncthreads();
    if (n >= N) return;
    int t = ntype[n];
    const float* wk = Wk + (size_t)t * DIM * DIM;
    const float* wq = Wq + (size_t)t * DIM * DIM;
    const float* wv = Wv + (size_t)t * DIM * DIM;
    float ak = 0.f, aq = 0.f, av = 0.f;
    #pragma unroll 16
    for (int d = 0; d < DIM; d++) {
        float x = hs[ln][d];
        ak = fmaf(x, wk[d * DIM + o], ak);
        aq = fmaf(x, wq[d * DIM + o], aq);
        av = fmaf(x, wv[d * DIM + o], av);
    }
    k[(size_t)n * DIM + o] = ak;
    q[(size_t)n * DIM + o] = aq;
    v[(size_t)n * DIM + o] = av;
}

// ---------------- CSR build: histogram of dst ----------------
__global__ void hist_kernel(const int* __restrict__ dst, int* __restrict__ cnt, int E) {
    int e = blockIdx.x * blockDim.x + threadIdx.x;
    if (e < E) atomicAdd(&cnt[dst[e]], 1);
}

// ------- 3-dispatch parallel exclusive scan: cnt[N] -> off[N+1] -------
__global__ void scan1(const int* __restrict__ cnt, int* __restrict__ off,
                      int* __restrict__ bsum, int N) {
    __shared__ int buf[1024];
    int tid = threadIdx.x;
    int i = blockIdx.x * 1024 + tid;
    int x = (i < N) ? cnt[i] : 0;
    buf[tid] = x;
    __syncthreads();
    for (int s = 1; s < 1024; s <<= 1) {
        int t = (tid >= s) ? buf[tid - s] : 0;
        __syncthreads();
        buf[tid] += t;
        __syncthreads();
    }
    if (i < N) off[i] = buf[tid] - x;            // block-local exclusive
    if (tid == 1023) bsum[blockIdx.x] = buf[1023];
}

__global__ void scan2(int* __restrict__ bsum, int nb) {
    __shared__ int buf[1024];
    __shared__ int carry;
    int tid = threadIdx.x;
    if (tid == 0) carry = 0;
    __syncthreads();
    for (int base = 0; base < nb; base += 1024) {
        int i = base + tid;
        int x = (i < nb) ? bsum[i] : 0;
        buf[tid] = x;
        __syncthreads();
        for (int s = 1; s < 1024; s <<= 1) {
            int t = (tid >= s) ? buf[tid - s] : 0;
            __syncthreads();
            buf[tid] += t;
            __syncthreads();
        }
        if (i < nb) bsum[i] = carry + buf[tid] - x;  // exclusive
        __syncthreads();
        if (tid == 1023) carry += buf[1023];
        __syncthreads();
    }
}

__global__ void scan3(int* __restrict__ off, const int* __restrict__ bsum, int N, int E) {
    int i = blockIdx.x * 1024 + threadIdx.x;
    if (i < N) off[i] += bsum[blockIdx.x];
    if (i == 0) off[N] = E;
}

// ------- scatter edges into dst-sorted order; pack (et<<24)|src -------
__global__ void scatter_kernel(const int* __restrict__ src, const int* __restrict__ dst,
                               const int* __restrict__ et, const int* __restrict__ off,
                               int* __restrict__ cnt2, int* __restrict__ se, int E) {
    int e = blockIdx.x * blockDim.x + threadIdx.x;
    if (e >= E) return;
    int d = dst[e];
    int p = off[d] + atomicAdd(&cnt2[d], 1);
    se[p] = (et[e] << 24) | src[e];
}

// ------- apply_rel as LDS-blocked GEMM: 64 nodes x 64 cols per block -------
// out[ry][n][o] = sum_d x[n][d] * Wr[r0+ry][d][o]
__global__ void apply_rel_gemm(const float* __restrict__ x, const float* __restrict__ Wr,
                               float* __restrict__ out, int N, int r0) {
    __shared__ float xs[64][68];     // pad 68: 2-way bank alias only (free); 272B rows keep float4 align
    __shared__ float wsm[64][64];    // 16 KB weight tile
    int t  = threadIdx.x;
    int r  = r0 + blockIdx.y;
    int n0 = blockIdx.x * 64;

    // stage W: 1024 float4, 4 per thread
    const float4* wg = (const float4*)(Wr + (size_t)r * DIM * DIM);
    float4* wl = (float4*)&wsm[0][0];
    #pragma unroll
    for (int i = 0; i < 4; i++) wl[t + 256 * i] = wg[t + 256 * i];

    // stage x tile: 1024 float4, 4 per thread
    #pragma unroll
    for (int i = 0; i < 4; i++) {
        int idx = t + 256 * i;        // float4 index within tile
        int row = idx >> 4, c4 = idx & 15;
        int gn = n0 + row;
        float4 xv = make_float4(0.f, 0.f, 0.f, 0.f);
        if (gn < N) xv = ((const float4*)(x + (size_t)gn * DIM))[c4];
        ((float4*)&xs[row][0])[c4] = xv;
    }
    __syncthreads();

    int og  = t & 15;       // output float4 column group
    int ng4 = (t >> 4) * 4; // first of this thread's 4 nodes
    float4 a0 = make_float4(0.f, 0.f, 0.f, 0.f);
    float4 a1 = a0, a2 = a0, a3 = a0;
    #pragma unroll 8
    for (int d = 0; d < DIM; d++) {
        float4 wv = ((const float4*)&wsm[d][0])[og];
        float x0 = xs[ng4 + 0][d];
        float x1 = xs[ng4 + 1][d];
        float x2 = xs[ng4 + 2][d];
        float x3 = xs[ng4 + 3][d];
        a0.x = fmaf(x0, wv.x, a0.x); a0.y = fmaf(x0, wv.y, a0.y);
        a0.z = fmaf(x0, wv.z, a0.z); a0.w = fmaf(x0, wv.w, a0.w);
        a1.x = fmaf(x1, wv.x, a1.x); a1.y = fmaf(x1, wv.y, a1.y);
        a1.z = fmaf(x1, wv.z, a1.z); a1.w = fmaf(x1, wv.w, a1.w);
        a2.x = fmaf(x2, wv.x, a2.x); a2.y = fmaf(x2, wv.y, a2.y);
        a2.z = fmaf(x2, wv.z, a2.z); a2.w = fmaf(x2, wv.w, a2.w);
        a3.x = fmaf(x3, wv.x, a3.x); a3.y = fmaf(x3, wv.y, a3.y);
        a3.z = fmaf(x3, wv.z, a3.z); a3.w = fmaf(x3, wv.w, a3.w);
    }
    float* ob = out + (size_t)blockIdx.y * N * DIM;
    if (n0 + ng4 + 0 < N) ((float4*)(ob + (size_t)(n0 + ng4 + 0) * DIM))[og] = a0;
    if (n0 + ng4 + 1 < N) ((float4*)(ob + (size_t)(n0 + ng4 + 1) * DIM))[og] = a1;
    if (n0 + ng4 + 2 < N) ((float4*)(ob + (size_t)(n0 + ng4 + 2) * DIM))[og] = a2;
    if (n0 + ng4 + 3 < N) ((float4*)(ob + (size_t)(n0 + ng4 + 3) * DIM))[og] = a3;
}

// ------- score over CSR: 16-lane group per dst node, no atomics -------
__global__ void score_csr(const float* __restrict__ qW, const float* __restrict__ k,
                          const int* __restrict__ se, const int* __restrict__ off,
                          const float* __restrict__ rel_pri,
                          float* __restrict__ ex, int N, int r0, int r1) {
    int n  = blockIdx.x * 16 + (threadIdx.x >> 4);
    int ll = threadIdx.x & 15;
    if (n >= N) return;
    int i0 = off[n], i1 = off[n + 1];
    for (int i = i0; i < i1; i++) {
        int sev = se[i];
        int r = sev >> 24;
        if (r < r0 || r >= r1) continue;
        int s = sev & SRC_MASK;
        float4 a = ((const float4*)(qW + ((size_t)(r - r0) * N + n) * DIM))[ll];
        float4 b = ((const float4*)(k + (size_t)s * DIM))[ll];
        float p = a.x * b.x + a.y * b.y + a.z * b.z + a.w * b.w;
        p += __shfl_xor(p, 8, 16);
        p += __shfl_xor(p, 4, 16);
        p += __shfl_xor(p, 2, 16);
        p += __shfl_xor(p, 1, 16);
        if (ll == 0) ex[i] = expf(p * rel_pri[r] * 0.125f);  // logits tiny: no max-shift needed
    }
}

// ------- per-node denominator over CSR range, no atomics -------
__global__ void den_csr(const float* __restrict__ ex, const int* __restrict__ off,
                        float* __restrict__ den, int N) {
    int n = blockIdx.x * blockDim.x + threadIdx.x;
    if (n >= N) return;
    int i0 = off[n], i1 = off[n + 1];
    float s = 0.f;
    for (int i = i0; i < i1; i++) s += ex[i];
    den[n] = s;
}

// ------- aggregate over CSR: 16-lane group per dst node, no atomics -------
__global__ void agg_csr(const float* __restrict__ vW, const float* __restrict__ ex,
                        const int* __restrict__ se, const int* __restrict__ off,
                        const float* __restrict__ den, float* __restrict__ agg,
                        int N, int r0, int r1, int first) {
    int n  = blockIdx.x * 16 + (threadIdx.x >> 4);
    int ll = threadIdx.x & 15;
    if (n >= N) return;
    int i0 = off[n], i1 = off[n + 1];
    float dn = den[n];
    float inv = (dn == 0.f) ? 0.f : 1.f / dn;
    float4 acc = make_float4(0.f, 0.f, 0.f, 0.f);
    for (int i = i0; i < i1; i++) {
        int sev = se[i];
        int r = sev >> 24;
        if (r < r0 || r >= r1) continue;
        int s = sev & SRC_MASK;
        float alpha = ex[i] * inv;
        float4 mv = ((const float4*)(vW + ((size_t)(r - r0) * N + s) * DIM))[ll];
        acc.x = fmaf(alpha, mv.x, acc.x);
        acc.y = fmaf(alpha, mv.y, acc.y);
        acc.z = fmaf(alpha, mv.z, acc.z);
        acc.w = fmaf(alpha, mv.w, acc.w);
    }
    float4* ap = (float4*)(agg + (size_t)n * DIM) + ll;
    if (first) *ap = acc;
    else {
        float4 o = *ap;
        o.x += acc.x; o.y += acc.y; o.z += acc.z; o.w += acc.w;
        *ap = o;
    }
}

// ------- output: per-node-type GEMM with sigmoid(skip) scaling -------
__global__ void out_kernel(const float* __restrict__ agg, const int* __restrict__ ntype,
                           const float* __restrict__ Wa, const float* __restrict__ skip,
                           float* __restrict__ out, int N) {
    __shared__ float xs[4][DIM];
    int ln = threadIdx.x >> 6;
    int o  = threadIdx.x & 63;
    int n  = blockIdx.x * 4 + ln;
    float xv = 0.f;
    if (n < N) xv = agg[(size_t)n * DIM + o];
    xs[ln][o] = xv;
    __syncthreads();
    if (n >= N) return;
    int t = ntype[n];
    float sg = 1.f / (1.f + expf(-skip[t]));
    const float* w = Wa + (size_t)t * DIM * DIM;
    float acc = 0.f;
    #pragma unroll 16
    for (int d = 0; d < DIM; d++)
        acc = fmaf(xs[ln][d], w[d * DIM + o], acc);
    out[(size_t)n * DIM + o] = acc * sg;
}

// ------- fallback (tiny ws): per-edge bilinear with atomics -------
__global__ void score_direct(const float* __restrict__ q, const float* __restrict__ k,
                             const int* __restrict__ src, const int* __restrict__ dst,
                             const int* __restrict__ et, const float* __restrict__ A,
                             const float* __restrict__ rel_pri,
                             float* __restrict__ ex, float* __restrict__ den, int E) {
    int e = (blockIdx.x * blockDim.x + threadIdx.x) >> 6;
    int l = threadIdx.x & 63;
    if (e >= E) return;
    int s = src[e], d = dst[e], r = et[e];
    float qv = q[(size_t)d * DIM + l];
    const float* a = A + (size_t)r * DIM * DIM;
    float t = 0.f;
    #pragma unroll 16
    for (int dd = 0; dd < DIM; dd++)
        t = fmaf(__shfl(qv, dd, 64), a[dd * DIM + l], t);
    float p = t * k[(size_t)s * DIM + l];
    #pragma unroll
    for (int off = 32; off > 0; off >>= 1) p += __shfl_xor(p, off, 64);
    if (l == 0) {
        float e_ = expf(p * rel_pri[r] * 0.125f);
        ex[e] = e_;
        atomicAdd(&den[d], e_);
    }
}

__global__ void agg_direct(const float* __restrict__ v, const float* __restrict__ ex,
                           const int* __restrict__ src, const int* __restrict__ dst,
                           const int* __restrict__ et, const float* __restrict__ Mw,
                           const float* __restrict__ den,
                           float* __restrict__ agg, int E) {
    int e = (blockIdx.x * blockDim.x + threadIdx.x) >> 6;
    int l = threadIdx.x & 63;
    if (e >= E) return;
    int s = src[e], d = dst[e], r = et[e];
    float vv = v[(size_t)s * DIM + l];
    const float* w = Mw + (size_t)r * DIM * DIM;
    float t = 0.f;
    #pragma unroll 16
    for (int dd = 0; dd < DIM; dd++)
        t = fmaf(__shfl(vv, dd, 64), w[dd * DIM + l], t);
    float dn = den[d];
    float alpha = ex[e] / (dn == 0.f ? 1.f : dn);
    atomicAdd(&agg[(size_t)d * DIM + l], alpha * t);
}

extern "C" void kernel_launch(void* const* d_in, const int* in_sizes, int n_in,
                              void* d_out, int out_size, void* d_ws, size_t ws_size,
                              hipStream_t stream) {
    const float* h       = (const float*)d_in[0];
    const int*   ntype   = (const int*)  d_in[1];
    const int*   src     = (const int*)  d_in[2];
    const int*   dst     = (const int*)  d_in[3];
    const int*   et      = (const int*)  d_in[4];
    const float* k_lin   = (const float*)d_in[5];
    const float* q_lin   = (const float*)d_in[6];
    const float* v_lin   = (const float*)d_in[7];
    const float* a_lin   = (const float*)d_in[8];
    const float* rel_att = (const float*)d_in[9];
    const float* rel_msg = (const float*)d_in[10];
    const float* rel_pri = (const float*)d_in[11];
    const float* skip    = (const float*)d_in[12];

    int N = in_sizes[1];   // node_type
    int E = in_sizes[2];   // src

    float* ws = (float*)d_ws;
    size_t o = 0;
    float* k    = ws + o; o += (size_t)N * DIM;   // overlaid by agg later
    float* q    = ws + o; o += (size_t)N * DIM;   // overlaid by den later
    float* v    = ws + o; o += (size_t)N * DIM;
    float* ex   = ws + o; o += (size_t)E;
    int*   off  = (int*)(ws + o); o += (size_t)N + 1;
    int*   cnt  = (int*)(ws + o); o += (size_t)N;
    int*   cnt2 = (int*)(ws + o); o += (size_t)N;
    int*   se   = (int*)(ws + o); o += (size_t)E;
    int*   bsum = (int*)(ws + o); o += 1024;
    size_t fixed = o;
    float* agg = k;   // k dead after score phase
    float* den = q;   // q dead after score-side apply_rel

    size_t ws_floats = ws_size / sizeof(float);
    size_t avail = (ws_floats > fixed) ? (ws_floats - fixed) : 0;
    int C = (int)(avail / ((size_t)N * DIM));
    if (C > NR) C = NR;
    float* rbuf = ws + fixed;

    float* out = (float*)d_out;

    proj_kqv<<<(N + 3) / 4, 256, 0, stream>>>(h, ntype, k_lin, q_lin, v_lin, k, q, v, N);

    if (C >= 1) {
        // ---- CSR build ----
        init_cnt<<<(N + 255) / 256, 256, 0, stream>>>(cnt, cnt2, N);
        hist_kernel<<<(E + 255) / 256, 256, 0, stream>>>(dst, cnt, E);
        int nb = (N + 1023) / 1024;
        scan1<<<nb, 1024, 0, stream>>>(cnt, off, bsum, N);
        scan2<<<1, 1024, 0, stream>>>(bsum, nb);
        scan3<<<nb, 1024, 0, stream>>>(off, bsum, N, E);
        scatter_kernel<<<(E + 255) / 256, 256, 0, stream>>>(src, dst, et, off, cnt2, se, E);

        int nb16 = (N + 15) / 16;
        int nb64 = (N + 63) / 64;
        // ---- score phase (chunked over relations) ----
        for (int r0 = 0; r0 < NR; r0 += C) {
            int r1 = r0 + C < NR ? r0 + C : NR;
            apply_rel_gemm<<<dim3(nb64, r1 - r0), 256, 0, stream>>>(q, rel_att, rbuf, N, r0);
            score_csr<<<nb16, 256, 0, stream>>>(rbuf, k, se, off, rel_pri, ex, N, r0, r1);
        }
        den_csr<<<(N + 255) / 256, 256, 0, stream>>>(ex, off, den, N);
        // ---- aggregate phase ----
        for (int r0 = 0; r0 < NR; r0 += C) {
            int r1 = r0 + C < NR ? r0 + C : NR;
            apply_rel_gemm<<<dim3(nb64, r1 - r0), 256, 0, stream>>>(v, rel_msg, rbuf, N, r0);
            agg_csr<<<nb16, 256, 0, stream>>>(rbuf, ex, se, off, den, agg, N, r0, r1,
                                              r0 == 0 ? 1 : 0);
        }
    } else {
        // ---- workspace-starved fallback: per-edge bilinear with atomics ----
        float* den_fb = (float*)cnt;   // N floats, zeroed below
        zero_f<<<(N + 255) / 256, 256, 0, stream>>>(den_fb, N);
        score_direct<<<(E + 3) / 4, 256, 0, stream>>>(q, k, src, dst, et, rel_att, rel_pri,
                                                      ex, den_fb, E);
        zero_f<<<(N * DIM + 255) / 256, 256, 0, stream>>>(agg, N * DIM);
        agg_direct<<<(E + 3) / 4, 256, 0, stream>>>(v, ex, src, dst, et, rel_msg,
                                                    den_fb, agg, E);
        den = den_fb;
    }

    out_kernel<<<(N + 3) / 4, 256, 0, stream>>>(agg, ntype, a_lin, skip, out, N);
}